// Round 1
// baseline (328.641 us; speedup 1.0000x reference)
//
#include <hip/hip_runtime.h>

// Cubic B-spline interpolation (SplineInter), 2D, m=1024x1024, PAD=2.
// coeffs (1028 x 1028) float32, flat-clamped gather per reference.
//
// R1: row-vectorized gathers (4x dwordx4 per point).
// R2: 2 points per thread, 8 hoisted row loads (MLP probe).
// R3: spatial counting-sort. Theory: the kernel is bound by per-cache-line
//     gather throughput (random 16B lane-requests -> ~65 distinct 64B lines
//     per wave instruction, all L1 misses). Sort points into 8x8-cell bins
//     (128x128 = 16384 bins, ~128 pts/bin) so a wave's stencils overlap:
//     distinct lines/instr drops ~5x and the bin footprint (~0.5KB) is
//     L1-resident. Pipeline: memset -> histogram -> scan -> scatter -> eval.
//     Falls back to the R2 direct kernel if ws_size is insufficient.

#define I1 1028
#define TOTAL (1028 * 1028)
#define NBINS 16384              // 128 x 128 bins of 8x8 cells

// 4-float vector with only 4-byte alignment guarantee (rows are not 16B-aligned).
typedef float f4u __attribute__((ext_vector_type(4), aligned(4)));

__device__ __forceinline__ void basis4(float t, float w[4]) {
    float a = 1.0f - t;
    w[0] = a * a * a;                                // j=-1: (1-t)^3
    w[1] = (3.0f * t - 6.0f) * (t * t) + 4.0f;       // j=0
    float xi = t - 1.0f;
    w[2] = -(3.0f * xi + 6.0f) * (xi * xi) + 4.0f;   // j=1
    w[3] = t * t * t;                                // j=2
}

struct PointSetup {
    int base;
    bool valid;
    bool interior;
    float w0[4], w1[4];
};

__device__ __forceinline__ PointSetup setup_point(float px, float py) {
    PointSetup ps;
    float xn0 = px * 1024.0f - 0.5f;
    float xn1 = py * 1024.0f - 0.5f;

    ps.valid = (xn0 > -2.0f) && (xn0 < 1024.0f) &&
               (xn1 > -2.0f) && (xn1 < 1024.0f);

    float P0f = floorf(xn0);
    float P1f = floorf(xn1);
    int P0 = (int)P0f;
    int P1 = (int)P1f;
    float t0 = xn0 - P0f;
    float t1 = xn1 - P1f;

    basis4(t0, ps.w0);
    basis4(t1, ps.w1);

    ps.base = I1 * (2 + P0) + (2 + P1);
    // Stencil spans [base - I1 - 1, base + 2*I1 + 2]; if fully in range the
    // element-wise flat clamp can never fire.
    ps.interior = (ps.base - I1 - 1 >= 0) && (ps.base + 2 * I1 + 2 <= TOTAL - 1);
    return ps;
}

__device__ __forceinline__ float eval_slow(const float* __restrict__ coeffs,
                                           const PointSetup& ps) {
    float acc = 0.0f;
#pragma unroll
    for (int j = 0; j < 4; ++j) {
        int r = ps.base + (j - 1) * I1 - 1;
        float s = 0.0f;
#pragma unroll
        for (int k = 0; k < 4; ++k) {
            int idx = r + k;
            idx = min(max(idx, 0), TOTAL - 1);  // flat clamp, matches jnp.clip
            s = fmaf(coeffs[idx], ps.w1[k], s);
        }
        acc = fmaf(s, ps.w0[j], acc);
    }
    return acc;
}

__device__ __forceinline__ float reduce_rows(const f4u v[4], const PointSetup& ps) {
    float acc = 0.0f;
#pragma unroll
    for (int j = 0; j < 4; ++j) {
        float s = fmaf(v[j].x, ps.w1[0],
                  fmaf(v[j].y, ps.w1[1],
                  fmaf(v[j].z, ps.w1[2],
                       v[j].w * ps.w1[3])));
        acc = fmaf(s, ps.w0[j], acc);
    }
    return acc;
}

// Bin id for the counting sort. Purely a locality heuristic: any mapping is
// CORRECT as long as hist and scatter agree, so clamping is safe.
__device__ __forceinline__ int bin_of(float px, float py) {
    float xn0 = px * 1024.0f - 0.5f;
    float xn1 = py * 1024.0f - 0.5f;
    int P0 = (int)floorf(xn0);
    int P1 = (int)floorf(xn1);
    int b0 = min(max(P0, 0), 1023) >> 3;   // 0..127
    int b1 = min(max(P1, 0), 1023) >> 3;   // 0..127
    return (b0 << 7) | b1;                 // row-major: b1 fastest (matches memory)
}

// ---------------- Pipeline kernels ----------------

__global__ __launch_bounds__(256) void hist_kernel(
    const float* __restrict__ x, int* __restrict__ counts, int n)
{
    int i = blockIdx.x * blockDim.x + threadIdx.x;
    int stride = gridDim.x * blockDim.x;
    for (; i < n; i += stride) {
        float2 xy = reinterpret_cast<const float2*>(x)[i];
        atomicAdd(&counts[bin_of(xy.x, xy.y)], 1);
    }
}

__global__ __launch_bounds__(1024) void scan_kernel(
    const int* __restrict__ counts, int* __restrict__ cursor)
{
    __shared__ int sdata[1024];
    int t = threadIdx.x;           // 0..1023, each owns 16 bins
    int local[16];
    int tot = 0;
#pragma unroll
    for (int k = 0; k < 16; ++k) {
        local[k] = counts[t * 16 + k];
        tot += local[k];
    }
    sdata[t] = tot;
    __syncthreads();
    // Hillis-Steele inclusive scan over 1024 partials
    for (int off = 1; off < 1024; off <<= 1) {
        int add = (t >= off) ? sdata[t - off] : 0;
        __syncthreads();
        sdata[t] += add;
        __syncthreads();
    }
    int run = sdata[t] - tot;      // exclusive prefix of this thread's segment
#pragma unroll
    for (int k = 0; k < 16; ++k) {
        cursor[t * 16 + k] = run;
        run += local[k];
    }
}

__global__ __launch_bounds__(256) void scatter_kernel(
    const float* __restrict__ x, int* __restrict__ cursor,
    float2* __restrict__ xs, int* __restrict__ sidx, int n)
{
    int i = blockIdx.x * blockDim.x + threadIdx.x;
    int stride = gridDim.x * blockDim.x;
    for (; i < n; i += stride) {
        float2 xy = reinterpret_cast<const float2*>(x)[i];
        int b = bin_of(xy.x, xy.y);
        int slot = atomicAdd(&cursor[b], 1);
        xs[slot] = xy;
        sidx[slot] = i;
    }
}

__global__ __launch_bounds__(256) void eval_sorted_kernel(
    const float2* __restrict__ xs, const int* __restrict__ sidx,
    const float* __restrict__ coeffs, float* __restrict__ out, int half)
{
    int g = blockIdx.x * blockDim.x + threadIdx.x;
    if (g >= half) return;

    // Two CONSECUTIVE sorted points per thread: preserves wave locality
    // (unlike the i/i+half split) and keeps 8 loads in flight.
    float4 two = reinterpret_cast<const float4*>(xs)[g];
    int2 id2 = reinterpret_cast<const int2*>(sidx)[g];

    PointSetup psA = setup_point(two.x, two.y);
    PointSetup psB = setup_point(two.z, two.w);

    float accA, accB;
    if (psA.interior && psB.interior) {
        f4u vA[4], vB[4];
#pragma unroll
        for (int j = 0; j < 4; ++j) {
            vA[j] = *reinterpret_cast<const f4u*>(coeffs + psA.base + (j - 1) * I1 - 1);
            vB[j] = *reinterpret_cast<const f4u*>(coeffs + psB.base + (j - 1) * I1 - 1);
        }
        accA = reduce_rows(vA, psA);
        accB = reduce_rows(vB, psB);
    } else {
        accA = eval_slow(coeffs, psA);
        accB = eval_slow(coeffs, psB);
    }

    out[id2.x] = psA.valid ? accA : 0.0f;
    out[id2.y] = psB.valid ? accB : 0.0f;
}

// ---------------- Fallback direct kernel (R2, proven) ----------------

__global__ __launch_bounds__(256) void spline_interp_kernel(
    const float* __restrict__ x,
    const float* __restrict__ coeffs,
    float* __restrict__ out,
    int n, int half)
{
    int i = blockIdx.x * blockDim.x + threadIdx.x;
    if (i >= half) return;
    int i2 = i + half;

    float2 xyA = reinterpret_cast<const float2*>(x)[i];
    float2 xyB = reinterpret_cast<const float2*>(x)[i2];

    PointSetup psA = setup_point(xyA.x, xyA.y);
    PointSetup psB = setup_point(xyB.x, xyB.y);

    float accA, accB;
    if (psA.interior && psB.interior) {
        f4u vA[4], vB[4];
#pragma unroll
        for (int j = 0; j < 4; ++j) {
            vA[j] = *reinterpret_cast<const f4u*>(coeffs + psA.base + (j - 1) * I1 - 1);
            vB[j] = *reinterpret_cast<const f4u*>(coeffs + psB.base + (j - 1) * I1 - 1);
        }
        accA = reduce_rows(vA, psA);
        accB = reduce_rows(vB, psB);
    } else {
        accA = eval_slow(coeffs, psA);
        accB = eval_slow(coeffs, psB);
    }

    out[i]  = psA.valid ? accA : 0.0f;
    out[i2] = psB.valid ? accB : 0.0f;
}

// ---------------- Launch ----------------

extern "C" void kernel_launch(void* const* d_in, const int* in_sizes, int n_in,
                              void* d_out, int out_size, void* d_ws, size_t ws_size,
                              hipStream_t stream) {
    const float* x = (const float*)d_in[0];       // [N,2]
    const float* coeffs = (const float*)d_in[1];  // [1028*1028]
    float* out = (float*)d_out;                   // [N]

    int n = in_sizes[0] / 2;   // number of points (2,097,152)

    // Workspace layout
    size_t o_counts = 0;
    size_t o_cursor = o_counts + (size_t)NBINS * 4;
    size_t o_sidx   = o_cursor + (size_t)NBINS * 4;
    size_t o_xs     = (o_sidx + (size_t)n * 4 + 15) & ~(size_t)15;
    size_t need     = o_xs + (size_t)n * 8;

    if (ws_size >= need && (n % 2) == 0) {
        char* ws = (char*)d_ws;
        int*    counts = (int*)(ws + o_counts);
        int*    cursor = (int*)(ws + o_cursor);
        int*    sidx   = (int*)(ws + o_sidx);
        float2* xs     = (float2*)(ws + o_xs);

        hipMemsetAsync(counts, 0, (size_t)NBINS * 4, stream);
        hist_kernel<<<2048, 256, 0, stream>>>(x, counts, n);
        scan_kernel<<<1, 1024, 0, stream>>>(counts, cursor);
        scatter_kernel<<<2048, 256, 0, stream>>>(x, cursor, xs, sidx, n);

        int half = n / 2;
        int grid = (half + 255) / 256;
        eval_sorted_kernel<<<grid, 256, 0, stream>>>(xs, sidx, coeffs, out, half);
    } else {
        // Fallback: proven R2 direct kernel
        int half = n / 2;
        int block = 256;
        int grid = (half + block - 1) / block;
        spline_interp_kernel<<<grid, block, 0, stream>>>(x, coeffs, out, n, half);
    }
}

// Round 2
// 106.960 us; speedup vs baseline: 3.0726x; 3.0726x over previous
//
#include <hip/hip_runtime.h>

// Cubic B-spline interpolation (SplineInter), 2D, m=1024x1024, PAD=2.
// coeffs (1028 x 1028) float32, flat-clamped gather per reference.
//
// R1: row-vectorized gathers (4x dwordx4 per point).
// R2: 2 points per thread, 8 hoisted row loads (MLP).  [109.7 us verified]
// R3: global counting sort — FAILED (scatter write-amp: 201 MB WRITE_SIZE,
//     160 us for scatter alone; random 12B records -> full-line evictions).
//     Sort abandoned: fixing it needs an LDS-staged 2-level radix whose best
//     case barely beats direct.
// R4: quad-row repack. Direct kernel costs ~34 CU-cyc/point; VALU ~0.4 -> the
//     gather path dominates. Repack coeffs into Q[qr][c] = float4 of 4
//     vertically adjacent rows (one ~4us streaming pre-pass into d_ws). The
//     4x4 stencil becomes 2 contiguous 64B regions (8 ALIGNED dwordx4),
//     ~3.5 distinct lines/point vs 4.75 unaligned before. Row phase (r0&3)
//     handled branchlessly with a shifted 8-wide weight vector (cndmasks).

#define I1 1028
#define TOTAL (1028 * 1028)
#define NQR 257                    // 1028 rows / 4 per quad
#define QELEMS (NQR * I1)          // 264196 float4 elements (~4.03 MB)

// 4-float vector with only 4-byte alignment guarantee (for the fallback path).
typedef float f4u __attribute__((ext_vector_type(4), aligned(4)));

__device__ __forceinline__ void basis4(float t, float w[4]) {
    float a = 1.0f - t;
    w[0] = a * a * a;                                // j=-1: (1-t)^3
    w[1] = (3.0f * t - 6.0f) * (t * t) + 4.0f;       // j=0
    float xi = t - 1.0f;
    w[2] = -(3.0f * xi + 6.0f) * (xi * xi) + 4.0f;   // j=1
    w[3] = t * t * t;                                // j=2
}

struct PointSetup {
    int base;        // flat index into padded grid (row-major, stride I1)
    int r0, c0;      // first stencil row/col in padded coords
    bool valid;
    bool qinterior;  // quad fast path legal: r0 in [0,1023], c0 >= 0
    float w0[4], w1[4];
};

__device__ __forceinline__ PointSetup setup_point(float px, float py) {
    PointSetup ps;
    float xn0 = px * 1024.0f - 0.5f;
    float xn1 = py * 1024.0f - 0.5f;

    ps.valid = (xn0 > -2.0f) && (xn0 < 1024.0f) &&
               (xn1 > -2.0f) && (xn1 < 1024.0f);

    float P0f = floorf(xn0);
    float P1f = floorf(xn1);
    int P0 = (int)P0f;
    int P1 = (int)P1f;
    float t0 = xn0 - P0f;
    float t1 = xn1 - P1f;

    basis4(t0, ps.w0);
    basis4(t1, ps.w1);

    ps.base = I1 * (2 + P0) + (2 + P1);
    ps.r0 = P0 + 1;   // first of 4 stencil rows (0..1027 when interior)
    ps.c0 = P1 + 1;   // first of 4 stencil cols
    // Quad path needs rows r0..r0+3 and cols c0..c0+3 fully in [0,1027]:
    // then the reference's flat clamp never fires and Q covers the stencil.
    ps.qinterior = (ps.r0 >= 0) && (ps.r0 <= 1023) &&
                   (ps.c0 >= 0) && (ps.c0 + 3 <= 1027);
    return ps;
}

__device__ __forceinline__ float eval_slow(const float* __restrict__ coeffs,
                                           const PointSetup& ps) {
    float acc = 0.0f;
#pragma unroll
    for (int j = 0; j < 4; ++j) {
        int r = ps.base + (j - 1) * I1 - 1;
        float s = 0.0f;
#pragma unroll
        for (int k = 0; k < 4; ++k) {
            int idx = r + k;
            idx = min(max(idx, 0), TOTAL - 1);  // flat clamp, matches jnp.clip
            s = fmaf(coeffs[idx], ps.w1[k], s);
        }
        acc = fmaf(s, ps.w0[j], acc);
    }
    return acc;
}

// Build 8-wide shifted row-weight vector: W[t] = w0[t-s] when t-s in [0,4), else 0.
// Fully unrolled, statically indexed (no scratch); conditions are s==const
// cndmasks which the compiler CSEs into 4 cmps.
__device__ __forceinline__ void shifted_w8(const float w0[4], int s, float W[8]) {
#pragma unroll
    for (int t = 0; t < 8; ++t) {
        float v = 0.0f;
        if (t - 0 >= 0 && t - 0 < 4) v = (s == 0) ? w0[t - 0] : v;
        if (t - 1 >= 0 && t - 1 < 4) v = (s == 1) ? w0[t - 1] : v;
        if (t - 2 >= 0 && t - 2 < 4) v = (s == 2) ? w0[t - 2] : v;
        if (t - 3 >= 0 && t - 3 < 4) v = (s == 3) ? w0[t - 3] : v;
        W[t] = v;
    }
}

__device__ __forceinline__ float reduce_quad(const float4 A[4], const float4 B[4],
                                             const float W[8], const float w1[4]) {
    float acc = 0.0f;
#pragma unroll
    for (int k = 0; k < 4; ++k) {
        float sk = fmaf(A[k].x, W[0],
                   fmaf(A[k].y, W[1],
                   fmaf(A[k].z, W[2],
                   fmaf(A[k].w, W[3],
                   fmaf(B[k].x, W[4],
                   fmaf(B[k].y, W[5],
                   fmaf(B[k].z, W[6],
                        B[k].w * W[7])))))));
        acc = fmaf(sk, w1[k], acc);
    }
    return acc;
}

// ---------------- Quad repack (streaming pre-pass) ----------------

__global__ __launch_bounds__(256) void quadpack_kernel(
    const float* __restrict__ coeffs, float4* __restrict__ Q)
{
    int i = blockIdx.x * blockDim.x + threadIdx.x;
    if (i >= QELEMS) return;
    int qr = i / I1;
    int c  = i - qr * I1;
    int r  = 4 * qr;
    float4 v;
    v.x = coeffs[(r + 0) * I1 + c];
    v.y = coeffs[(r + 1) * I1 + c];
    v.z = coeffs[(r + 2) * I1 + c];
    v.w = coeffs[(r + 3) * I1 + c];
    Q[i] = v;
}

// ---------------- Eval on quad layout ----------------

__global__ __launch_bounds__(256) void eval_quad_kernel(
    const float* __restrict__ x,      // [N,2] interleaved
    const float* __restrict__ coeffs, // original (slow path)
    const float4* __restrict__ Q,     // quad-packed
    float* __restrict__ out, int n)
{
    int g = blockIdx.x * blockDim.x + threadIdx.x;
    int i0 = 2 * g;
    if (i0 >= n) return;

    if (i0 + 1 < n) {
        // Two consecutive points: one coalesced float4 x-load, float2 out-store.
        float4 two = reinterpret_cast<const float4*>(x)[g];
        PointSetup psA = setup_point(two.x, two.y);
        PointSetup psB = setup_point(two.z, two.w);

        float accA, accB;
        if (psA.qinterior && psB.qinterior) {
            int sA = psA.r0 & 3, sB = psB.r0 & 3;
            const float4* qA = Q + (psA.r0 >> 2) * I1 + psA.c0;
            const float4* qB = Q + (psB.r0 >> 2) * I1 + psB.c0;
            // Hoist all loads: 2 points x 2 regions x 4 aligned dwordx4.
            float4 A0[4], A1[4], B0[4], B1[4];
#pragma unroll
            for (int k = 0; k < 4; ++k) {
                A0[k] = qA[k];
                B0[k] = qB[k];
            }
#pragma unroll
            for (int k = 0; k < 4; ++k) {
                A1[k] = qA[I1 + k];
                B1[k] = qB[I1 + k];
            }
            float WA[8], WB[8];
            shifted_w8(psA.w0, sA, WA);
            shifted_w8(psB.w0, sB, WB);
            accA = reduce_quad(A0, A1, WA, psA.w1);
            accB = reduce_quad(B0, B1, WB, psB.w1);
        } else {
            accA = eval_slow(coeffs, psA);
            accB = eval_slow(coeffs, psB);
        }

        float2 o;
        o.x = psA.valid ? accA : 0.0f;
        o.y = psB.valid ? accB : 0.0f;
        reinterpret_cast<float2*>(out)[g] = o;
    } else {
        // odd tail point
        float px = x[2 * i0], py = x[2 * i0 + 1];
        PointSetup ps = setup_point(px, py);
        float acc = eval_slow(coeffs, ps);
        out[i0] = ps.valid ? acc : 0.0f;
    }
}

// ---------------- Fallback direct kernel (R2, proven) ----------------

__global__ __launch_bounds__(256) void spline_interp_kernel(
    const float* __restrict__ x,
    const float* __restrict__ coeffs,
    float* __restrict__ out,
    int n, int half)
{
    int i = blockIdx.x * blockDim.x + threadIdx.x;
    if (i >= half) return;
    int i2 = i + half;

    float2 xyA = reinterpret_cast<const float2*>(x)[i];
    float2 xyB = reinterpret_cast<const float2*>(x)[i2];

    PointSetup psA = setup_point(xyA.x, xyA.y);
    PointSetup psB = setup_point(xyB.x, xyB.y);

    float accA, accB;
    bool interiorA = (psA.base - I1 - 1 >= 0) && (psA.base + 2 * I1 + 2 <= TOTAL - 1);
    bool interiorB = (psB.base - I1 - 1 >= 0) && (psB.base + 2 * I1 + 2 <= TOTAL - 1);
    if (interiorA && interiorB) {
        f4u vA[4], vB[4];
#pragma unroll
        for (int j = 0; j < 4; ++j) {
            vA[j] = *reinterpret_cast<const f4u*>(coeffs + psA.base + (j - 1) * I1 - 1);
            vB[j] = *reinterpret_cast<const f4u*>(coeffs + psB.base + (j - 1) * I1 - 1);
        }
        float a0 = 0.0f, a1 = 0.0f;
#pragma unroll
        for (int j = 0; j < 4; ++j) {
            float s0 = fmaf(vA[j].x, psA.w1[0], fmaf(vA[j].y, psA.w1[1],
                       fmaf(vA[j].z, psA.w1[2], vA[j].w * psA.w1[3])));
            a0 = fmaf(s0, psA.w0[j], a0);
            float s1 = fmaf(vB[j].x, psB.w1[0], fmaf(vB[j].y, psB.w1[1],
                       fmaf(vB[j].z, psB.w1[2], vB[j].w * psB.w1[3])));
            a1 = fmaf(s1, psB.w0[j], a1);
        }
        accA = a0; accB = a1;
    } else {
        accA = eval_slow(coeffs, psA);
        accB = eval_slow(coeffs, psB);
    }

    out[i]  = psA.valid ? accA : 0.0f;
    out[i2] = psB.valid ? accB : 0.0f;
}

// ---------------- Launch ----------------

extern "C" void kernel_launch(void* const* d_in, const int* in_sizes, int n_in,
                              void* d_out, int out_size, void* d_ws, size_t ws_size,
                              hipStream_t stream) {
    const float* x = (const float*)d_in[0];       // [N,2]
    const float* coeffs = (const float*)d_in[1];  // [1028*1028]
    float* out = (float*)d_out;                   // [N]

    int n = in_sizes[0] / 2;   // number of points (2,097,152)

    // Workspace: quad-packed coeffs, 16B-aligned.
    size_t o_q  = 0;
    size_t need = (size_t)QELEMS * 16;

    if (ws_size >= need) {
        float4* Q = (float4*)((char*)d_ws + o_q);

        int gpack = (QELEMS + 255) / 256;
        quadpack_kernel<<<gpack, 256, 0, stream>>>(coeffs, Q);

        int pairs = (n + 1) / 2;
        int geval = (pairs + 255) / 256;
        eval_quad_kernel<<<geval, 256, 0, stream>>>(x, coeffs, Q, out, n);
    } else {
        // Fallback: proven R2 direct kernel
        int half = n / 2;
        int block = 256;
        int grid = (half + block - 1) / block;
        spline_interp_kernel<<<grid, block, 0, stream>>>(x, coeffs, out, n, half);
    }
}